// Round 12
// baseline (711.328 us; speedup 1.0000x reference)
//
#include <hip/hip_runtime.h>
#include <hip/hip_bf16.h>

#define N_NODES 100000
#define N_EDGES 3200000
#define F_IN    512
#define F_H     16
#define F_OUT   7
#define NB      391                 // buckets of 256 dst nodes
#define GPART   512                 // partition blocks
#define PER_BLK 6256                // multiple of 4; 512*6256 >= 3.2M (last block short)
#define NTILES  6250                // 100000 / 16 row-tiles

typedef unsigned int u32;
typedef __attribute__((ext_vector_type(8))) __bf16 bf16x8;
typedef __attribute__((ext_vector_type(4))) float f32x4;

union FragU { uint4 q; bf16x8 v; };

static __device__ __forceinline__ float bflo(u32 u) { return __uint_as_float(u << 16); }
static __device__ __forceinline__ float bfhi(u32 u) { return __uint_as_float(u & 0xFFFF0000u); }
static __device__ __forceinline__ unsigned short f2bf(float f) {
  u32 x = __float_as_uint(f);
  x += 0x7FFF + ((x >> 16) & 1);    // round-to-nearest-even (finite values)
  return (unsigned short)(x >> 16);
}
// pack two fp32 -> two bf16 in one u32 (low16 = a, high16 = b)
static __device__ __forceinline__ u32 cvt2(float a, float b) {
  u32 r;
  asm("v_cvt_pk_bf16_f32 %0, %1, %2" : "=v"(r) : "v"(a), "v"(b));
  return r;
}

// ------ bucket histogram (per-block rows + bucket totals) + global deg ------
__global__ __launch_bounds__(256) void k_hist(const int* __restrict__ dst,
                                              int* __restrict__ hist,
                                              int* __restrict__ bcnt,
                                              int* __restrict__ deg) {
  __shared__ int h[NB];
  int tid = threadIdx.x, blk = blockIdx.x;
  for (int b = tid; b < NB; b += 256) h[b] = 0;
  __syncthreads();
  int e0 = blk * PER_BLK;
  int n = min(PER_BLK, N_EDGES - e0);            // multiple of 4
  const int4* d4 = (const int4*)(dst + e0);
  for (int i = tid; i < (n >> 2); i += 256) {
    int4 d = d4[i];
    atomicAdd(&h[d.x >> 8], 1); atomicAdd(&deg[d.x], 1);
    atomicAdd(&h[d.y >> 8], 1); atomicAdd(&deg[d.y], 1);
    atomicAdd(&h[d.z >> 8], 1); atomicAdd(&deg[d.z], 1);
    atomicAdd(&h[d.w >> 8], 1); atomicAdd(&deg[d.w], 1);
  }
  __syncthreads();
  for (int b = tid; b < NB; b += 256) {
    int c = h[b];
    hist[blk * NB + b] = c;                      // block-major per-block counts
    if (c) atomicAdd(&bcnt[b], c);               // bucket totals
  }
}

// ---- grid=2: block 0 = bucket-base scan; block 1 = W1 bf16 B-fragment table ----
__global__ __launch_bounds__(512) void k_scanprep(const int* __restrict__ bcnt,
                                                  int* __restrict__ pbase,
                                                  int* __restrict__ gcur,
                                                  const float* __restrict__ W1,
                                                  uint4* __restrict__ bfragG) {
  int tid = threadIdx.x;
  if (blockIdx.x == 1) {
    // B-fragment for mfma_f32_16x16x32_bf16: lane l holds B[k=(l>>4)*8+j][col=l&15]
    for (int idx = tid; idx < 1024; idx += 512) {  // 16 kk * 64 lanes
      int kk = idx >> 6, lane = idx & 63;
      int col = lane & 15, g = lane >> 4;
      int k0 = kk * 32 + g * 8;
      uint4 q;
      q.x = cvt2(W1[(k0 + 0) * 16 + col], W1[(k0 + 1) * 16 + col]);
      q.y = cvt2(W1[(k0 + 2) * 16 + col], W1[(k0 + 3) * 16 + col]);
      q.z = cvt2(W1[(k0 + 4) * 16 + col], W1[(k0 + 5) * 16 + col]);
      q.w = cvt2(W1[(k0 + 6) * 16 + col], W1[(k0 + 7) * 16 + col]);
      bfragG[idx] = q;
    }
    return;
  }
  __shared__ int lds[512];
  int c = (tid < NB) ? bcnt[tid] : 0;
  lds[tid] = c;
  __syncthreads();
  for (int off = 1; off < 512; off <<= 1) {
    int v = (tid >= off) ? lds[tid - off] : 0;
    __syncthreads();
    lds[tid] += v;
    __syncthreads();
  }
  int ex = lds[tid] - c;
  if (tid <= NB) pbase[tid] = ex;     // pbase[NB] == N_EDGES (total)
  if (tid < NB) gcur[tid] = ex;
}

// -------- partition scatter: reserve ranges atomically, LDS cursors --------
// pack: (dst_local << 17) | src
__global__ __launch_bounds__(256) void k_part(const int* __restrict__ src,
                                              const int* __restrict__ dst,
                                              const int* __restrict__ hist,
                                              int* __restrict__ gcur,
                                              u32* __restrict__ pairs) {
  __shared__ int lbase[NB];
  __shared__ int lcur[NB];
  int tid = threadIdx.x, blk = blockIdx.x;
  for (int b = tid; b < NB; b += 256) {
    int c = hist[blk * NB + b];
    lbase[b] = c ? atomicAdd(&gcur[b], c) : 0;
    lcur[b] = 0;
  }
  __syncthreads();
  int e0 = blk * PER_BLK;
  int n = min(PER_BLK, N_EDGES - e0);            // multiple of 4
  const int4* s4 = (const int4*)(src + e0);
  const int4* d4 = (const int4*)(dst + e0);
  for (int i = tid; i < (n >> 2); i += 256) {
    int4 sv = s4[i];
    int4 dv = d4[i];
    { int b = dv.x >> 8; u32 v = ((u32)(dv.x & 255) << 17) | (u32)sv.x;
      pairs[lbase[b] + atomicAdd(&lcur[b], 1)] = v; }
    { int b = dv.y >> 8; u32 v = ((u32)(dv.y & 255) << 17) | (u32)sv.y;
      pairs[lbase[b] + atomicAdd(&lcur[b], 1)] = v; }
    { int b = dv.z >> 8; u32 v = ((u32)(dv.z & 255) << 17) | (u32)sv.z;
      pairs[lbase[b] + atomicAdd(&lcur[b], 1)] = v; }
    { int b = dv.w >> 8; u32 v = ((u32)(dv.w & 255) << 17) | (u32)sv.w;
      pairs[lbase[b] + atomicAdd(&lcur[b], 1)] = v; }
  }
}

// -------- GEMM1 via MFMA + LDS staging; writes h1p = bf16(dinv*h1) directly ----
__global__ __launch_bounds__(256) void k_gemm1(const float* __restrict__ x,
                                               const uint4* __restrict__ bfragG,
                                               const int* __restrict__ deg,
                                               unsigned short* __restrict__ h1p) {
  __shared__ __align__(16) char ldsbuf[2][64 * 80];   // 10 KB
  int tid = threadIdx.x;
  int blockRow0 = blockIdx.x * 64;

  // staging: thread covers rows r0 (=tid>>3) and r1 (=r0+32), slot s=tid&7
  int r0 = tid >> 3, r1 = r0 + 32, s = tid & 7;
  bool ok1 = (blockRow0 + r1) < N_NODES;
  const float* x0 = x + (size_t)(blockRow0 + r0) * F_IN + s * 4;
  const float* x1 = x + (size_t)(blockRow0 + r1) * F_IN + s * 4;

  int wv = tid >> 6, lane = tid & 63;
  int col = lane & 15, g = lane >> 4;
  int wid = blockIdx.x * 4 + wv;
  int fragRow = wv * 16 + col;

  f32x4 acc = {0.f, 0.f, 0.f, 0.f};

  {
    float4 fA = *(const float4*)(x0);
    float4 fB = ok1 ? *(const float4*)(x1) : make_float4(0.f, 0.f, 0.f, 0.f);
    uint2 qA = {cvt2(fA.x, fA.y), cvt2(fA.z, fA.w)};
    uint2 qB = {cvt2(fB.x, fB.y), cvt2(fB.z, fB.w)};
    *(uint2*)(&ldsbuf[0][r0 * 80 + s * 8]) = qA;
    *(uint2*)(&ldsbuf[0][r1 * 80 + s * 8]) = qB;
  }
  __syncthreads();

#pragma unroll
  for (int kk = 0; kk < 16; kk++) {
    int cur = kk & 1;
    float4 fA, fB;
    if (kk < 15) {
      fA = *(const float4*)(x0 + (kk + 1) * 32);
      fB = ok1 ? *(const float4*)(x1 + (kk + 1) * 32) : make_float4(0.f, 0.f, 0.f, 0.f);
    }
    FragU a, b;
    a.q = *(const uint4*)(&ldsbuf[cur][fragRow * 80 + g * 16]);
    b.q = bfragG[kk * 64 + lane];
    acc = __builtin_amdgcn_mfma_f32_16x16x32_bf16(a.v, b.v, acc, 0, 0, 0);
    if (kk < 15) {
      uint2 qA = {cvt2(fA.x, fA.y), cvt2(fA.z, fA.w)};
      uint2 qB = {cvt2(fB.x, fB.y), cvt2(fB.z, fB.w)};
      *(uint2*)(&ldsbuf[cur ^ 1][r0 * 80 + s * 8]) = qA;
      *(uint2*)(&ldsbuf[cur ^ 1][r1 * 80 + s * 8]) = qB;
    }
    __syncthreads();
  }

  // D: col = lane&15 (feature), row = (lane>>4)*4 + r; fold dinv, store bf16
#pragma unroll
  for (int r = 0; r < 4; r++) {
    int node = wid * 16 + g * 4 + r;
    if (node < N_NODES) {
      float di = rsqrtf((float)(deg[node] + 1));
      h1p[(size_t)node * F_H + col] = f2bf(di * acc[r]);
    }
  }
}

// ====== agg1 edge-parallel: LDS fp32 scatter-accum + (bias,ReLU,W2,fold) ======
__global__ __launch_bounds__(512) void k_agg1(const u32* __restrict__ pairs,
                                              const int* __restrict__ pbase,
                                              const int* __restrict__ deg,
                                              const unsigned short* __restrict__ h1p,
                                              const float* __restrict__ b1,
                                              const float* __restrict__ W2,
                                              unsigned short* __restrict__ gfp) {
  __shared__ float acc[256 * 17];                // stride 17: banks spread, 17.4 KB
  int tid = threadIdx.x, b = blockIdx.x;
  for (int i = tid; i < 256 * 17; i += 512) acc[i] = 0.f;
  __syncthreads();
  int base = pbase[b], cnt = pbase[b + 1] - base;
  const uint4* hp = (const uint4*)h1p;           // row n -> uint4 n*2, n*2+1
  for (int k = tid; k < cnt; k += 512) {
    u32 v = pairs[base + k];
    int dl = v >> 17;
    int src = v & 0x1FFFF;
    uint4 h0 = hp[src * 2], h1v = hp[src * 2 + 1];
    float* a = &acc[dl * 17];
    atomicAdd(a + 0,  bflo(h0.x));  atomicAdd(a + 1,  bfhi(h0.x));
    atomicAdd(a + 2,  bflo(h0.y));  atomicAdd(a + 3,  bfhi(h0.y));
    atomicAdd(a + 4,  bflo(h0.z));  atomicAdd(a + 5,  bfhi(h0.z));
    atomicAdd(a + 6,  bflo(h0.w));  atomicAdd(a + 7,  bfhi(h0.w));
    atomicAdd(a + 8,  bflo(h1v.x)); atomicAdd(a + 9,  bfhi(h1v.x));
    atomicAdd(a + 10, bflo(h1v.y)); atomicAdd(a + 11, bfhi(h1v.y));
    atomicAdd(a + 12, bflo(h1v.z)); atomicAdd(a + 13, bfhi(h1v.z));
    atomicAdd(a + 14, bflo(h1v.w)); atomicAdd(a + 15, bfhi(h1v.w));
  }
  __syncthreads();
  int node = b * 256 + tid;
  if (tid < 256 && node < N_NODES) {
    float di = rsqrtf((float)(deg[node] + 1));
    uint4 s0 = hp[node * 2], s1 = hp[node * 2 + 1];
    float* a = &acc[tid * 17];
    float hrow[16];
    hrow[0]  = fmaxf(di * (a[0]  + bflo(s0.x)) + b1[0],  0.f);
    hrow[1]  = fmaxf(di * (a[1]  + bfhi(s0.x)) + b1[1],  0.f);
    hrow[2]  = fmaxf(di * (a[2]  + bflo(s0.y)) + b1[2],  0.f);
    hrow[3]  = fmaxf(di * (a[3]  + bfhi(s0.y)) + b1[3],  0.f);
    hrow[4]  = fmaxf(di * (a[4]  + bflo(s0.z)) + b1[4],  0.f);
    hrow[5]  = fmaxf(di * (a[5]  + bfhi(s0.z)) + b1[5],  0.f);
    hrow[6]  = fmaxf(di * (a[6]  + bflo(s0.w)) + b1[6],  0.f);
    hrow[7]  = fmaxf(di * (a[7]  + bfhi(s0.w)) + b1[7],  0.f);
    hrow[8]  = fmaxf(di * (a[8]  + bflo(s1.x)) + b1[8],  0.f);
    hrow[9]  = fmaxf(di * (a[9]  + bfhi(s1.x)) + b1[9],  0.f);
    hrow[10] = fmaxf(di * (a[10] + bflo(s1.y)) + b1[10], 0.f);
    hrow[11] = fmaxf(di * (a[11] + bfhi(s1.y)) + b1[11], 0.f);
    hrow[12] = fmaxf(di * (a[12] + bflo(s1.z)) + b1[12], 0.f);
    hrow[13] = fmaxf(di * (a[13] + bfhi(s1.z)) + b1[13], 0.f);
    hrow[14] = fmaxf(di * (a[14] + bflo(s1.w)) + b1[14], 0.f);
    hrow[15] = fmaxf(di * (a[15] + bfhi(s1.w)) + b1[15], 0.f);
    float o[7] = {0.f, 0.f, 0.f, 0.f, 0.f, 0.f, 0.f};
#pragma unroll
    for (int k = 0; k < 16; k++)
#pragma unroll
      for (int j = 0; j < 7; j++) o[j] += hrow[k] * W2[k * 7 + j];
    uint4 q;
    q.x = cvt2(di * o[0], di * o[1]);
    q.y = cvt2(di * o[2], di * o[3]);
    q.z = cvt2(di * o[4], di * o[5]);
    q.w = cvt2(di * o[6], 0.f);
    ((uint4*)gfp)[node] = q;
  }
}

// ====== agg2 edge-parallel: LDS fp32 scatter-accum + bias + log_softmax ======
__global__ __launch_bounds__(512) void k_agg2(const u32* __restrict__ pairs,
                                              const int* __restrict__ pbase,
                                              const int* __restrict__ deg,
                                              const unsigned short* __restrict__ gfp,
                                              const float* __restrict__ b2,
                                              float* __restrict__ out) {
  __shared__ float acc[256 * 9];                 // stride 9, 9.2 KB
  int tid = threadIdx.x, b = blockIdx.x;
  for (int i = tid; i < 256 * 9; i += 512) acc[i] = 0.f;
  __syncthreads();
  int base = pbase[b], cnt = pbase[b + 1] - base;
  const uint4* gp = (const uint4*)gfp;           // row n -> uint4 n
  for (int k = tid; k < cnt; k += 512) {
    u32 v = pairs[base + k];
    int dl = v >> 17;
    int src = v & 0x1FFFF;
    uint4 g0 = gp[src];
    float* a = &acc[dl * 9];
    atomicAdd(a + 0, bflo(g0.x)); atomicAdd(a + 1, bfhi(g0.x));
    atomicAdd(a + 2, bflo(g0.y)); atomicAdd(a + 3, bfhi(g0.y));
    atomicAdd(a + 4, bflo(g0.z)); atomicAdd(a + 5, bfhi(g0.z));
    atomicAdd(a + 6, bflo(g0.w));                // feat 7 is zero pad: skip
  }
  __syncthreads();
  int node = b * 256 + tid;
  if (tid < 256 && node < N_NODES) {
    float di = rsqrtf((float)(deg[node] + 1));
    uint4 s0 = gp[node];
    float* a = &acc[tid * 9];
    float v[7];
    v[0] = di * (a[0] + bflo(s0.x)) + b2[0];
    v[1] = di * (a[1] + bfhi(s0.x)) + b2[1];
    v[2] = di * (a[2] + bflo(s0.y)) + b2[2];
    v[3] = di * (a[3] + bfhi(s0.y)) + b2[3];
    v[4] = di * (a[4] + bflo(s0.z)) + b2[4];
    v[5] = di * (a[5] + bfhi(s0.z)) + b2[5];
    v[6] = di * (a[6] + bflo(s0.w)) + b2[6];
    float m = v[0];
#pragma unroll
    for (int j = 1; j < 7; j++) m = fmaxf(m, v[j]);
    float s = 0.f;
#pragma unroll
    for (int j = 0; j < 7; j++) s += __expf(v[j] - m);
    float ls = m + logf(s);
#pragma unroll
    for (int j = 0; j < 7; j++) out[(size_t)node * 7 + j] = v[j] - ls;
  }
}

extern "C" void kernel_launch(void* const* d_in, const int* in_sizes, int n_in,
                              void* d_out, int out_size, void* d_ws, size_t ws_size,
                              hipStream_t stream) {
  const float* x  = (const float*)d_in[0];
  const int*   ei = (const int*)d_in[1];     // [0..E)=src, [E..2E)=dst (int32)
  const float* W1 = (const float*)d_in[2];
  const float* b1 = (const float*)d_in[3];
  const float* W2 = (const float*)d_in[4];
  const float* b2 = (const float*)d_in[5];
  float* out = (float*)d_out;

  // workspace layout (~18.8 MB; d_ws ~800 MB)
  char* base = (char*)d_ws;
  int*   bcnt   = (int*)(base + 0);            //      2,048
  int*   deg    = (int*)(base + 2048);         //    400,128   [memset covers bcnt+deg]
  int*   pbase  = (int*)(base + 402176);       //      2,048
  int*   gcur   = (int*)(base + 404224);       //      2,048
  uint4* bfragG = (uint4*)(base + 406272);     //     16,384
  int*   hist   = (int*)(base + 422656);       //    800,768 (GPART*NB*4)
  u32*   pairs  = (u32*)(base + 1223424);      // 12.8 MB  (ends 14,023,424)
  unsigned short* h1p = (unsigned short*)(base + 14023424); // 3.2 MB (ends 17,223,424)
  unsigned short* gfp = (unsigned short*)(base + 17223424); // 1.6 MB (ends 18,823,424)

  hipMemsetAsync(base, 0, 402176, stream);     // bcnt + deg

  k_hist    <<<GPART, 256, 0, stream>>>(ei + N_EDGES, hist, bcnt, deg);
  k_scanprep<<<2, 512, 0, stream>>>(bcnt, pbase, gcur, W1, bfragG);
  k_part    <<<GPART, 256, 0, stream>>>(ei, ei + N_EDGES, hist, gcur, pairs);
  k_gemm1   <<<(NTILES + 3) / 4, 256, 0, stream>>>(x, bfragG, deg, h1p);
  k_agg1    <<<NB, 512, 0, stream>>>(pairs, pbase, deg, h1p, b1, W2, gfp);
  k_agg2    <<<NB, 512, 0, stream>>>(pairs, pbase, deg, gfp, b2, out);
}

// Round 13
// 276.853 us; speedup vs baseline: 2.5693x; 2.5693x over previous
//
#include <hip/hip_runtime.h>
#include <hip/hip_bf16.h>

#define N_NODES 100000
#define N_EDGES 3200000
#define F_IN    512
#define F_H     16
#define F_OUT   7
#define NB      391                 // buckets of 256 dst nodes
#define GPART   512                 // partition blocks
#define PER_BLK 6256                // multiple of 4; 512*6256 >= 3.2M (last block short)
#define NTILES  6250                // 100000 / 16 row-tiles
#define CAPB    10240               // per-bucket edge cap (mean 8184, sigma~90 -> 22 sigma)

typedef unsigned int u32;
typedef __attribute__((ext_vector_type(8))) __bf16 bf16x8;
typedef __attribute__((ext_vector_type(4))) float f32x4;

union FragU { uint4 q; bf16x8 v; };

static __device__ __forceinline__ float bflo(u32 u) { return __uint_as_float(u << 16); }
static __device__ __forceinline__ float bfhi(u32 u) { return __uint_as_float(u & 0xFFFF0000u); }
static __device__ __forceinline__ unsigned short f2bf(float f) {
  u32 x = __float_as_uint(f);
  x += 0x7FFF + ((x >> 16) & 1);    // round-to-nearest-even (finite values)
  return (unsigned short)(x >> 16);
}
// pack two fp32 -> two bf16 in one u32 (low16 = a, high16 = b)
static __device__ __forceinline__ u32 cvt2(float a, float b) {
  u32 r;
  asm("v_cvt_pk_bf16_f32 %0, %1, %2" : "=v"(r) : "v"(a), "v"(b));
  return r;
}

// ------ bucket histogram (per-block rows + bucket totals) + global deg ------
__global__ __launch_bounds__(256) void k_hist(const int* __restrict__ dst,
                                              int* __restrict__ hist,
                                              int* __restrict__ bcnt,
                                              int* __restrict__ deg) {
  __shared__ int h[NB];
  int tid = threadIdx.x, blk = blockIdx.x;
  for (int b = tid; b < NB; b += 256) h[b] = 0;
  __syncthreads();
  int e0 = blk * PER_BLK;
  int n = min(PER_BLK, N_EDGES - e0);            // multiple of 4
  const int4* d4 = (const int4*)(dst + e0);
  for (int i = tid; i < (n >> 2); i += 256) {
    int4 d = d4[i];
    atomicAdd(&h[d.x >> 8], 1); atomicAdd(&deg[d.x], 1);
    atomicAdd(&h[d.y >> 8], 1); atomicAdd(&deg[d.y], 1);
    atomicAdd(&h[d.z >> 8], 1); atomicAdd(&deg[d.z], 1);
    atomicAdd(&h[d.w >> 8], 1); atomicAdd(&deg[d.w], 1);
  }
  __syncthreads();
  for (int b = tid; b < NB; b += 256) {
    int c = h[b];
    hist[blk * NB + b] = c;                      // block-major per-block counts
    if (c) atomicAdd(&bcnt[b], c);               // bucket totals
  }
}

// ---- grid=2: block 0 = bucket-base scan; block 1 = W1 bf16 B-fragment table ----
__global__ __launch_bounds__(512) void k_scanprep(const int* __restrict__ bcnt,
                                                  int* __restrict__ pbase,
                                                  int* __restrict__ gcur,
                                                  const float* __restrict__ W1,
                                                  uint4* __restrict__ bfragG) {
  int tid = threadIdx.x;
  if (blockIdx.x == 1) {
    // B-fragment for mfma_f32_16x16x32_bf16: lane l holds B[k=(l>>4)*8+j][col=l&15]
    for (int idx = tid; idx < 1024; idx += 512) {  // 16 kk * 64 lanes
      int kk = idx >> 6, lane = idx & 63;
      int col = lane & 15, g = lane >> 4;
      int k0 = kk * 32 + g * 8;
      uint4 q;
      q.x = cvt2(W1[(k0 + 0) * 16 + col], W1[(k0 + 1) * 16 + col]);
      q.y = cvt2(W1[(k0 + 2) * 16 + col], W1[(k0 + 3) * 16 + col]);
      q.z = cvt2(W1[(k0 + 4) * 16 + col], W1[(k0 + 5) * 16 + col]);
      q.w = cvt2(W1[(k0 + 6) * 16 + col], W1[(k0 + 7) * 16 + col]);
      bfragG[idx] = q;
    }
    return;
  }
  __shared__ int lds[512];
  int c = (tid < NB) ? bcnt[tid] : 0;
  lds[tid] = c;
  __syncthreads();
  for (int off = 1; off < 512; off <<= 1) {
    int v = (tid >= off) ? lds[tid - off] : 0;
    __syncthreads();
    lds[tid] += v;
    __syncthreads();
  }
  int ex = lds[tid] - c;
  if (tid <= NB) pbase[tid] = ex;     // pbase[NB] == N_EDGES (total)
  if (tid < NB) gcur[tid] = ex;
}

// -------- partition scatter: reserve ranges atomically, LDS cursors --------
// pack: (dst_local << 17) | src
__global__ __launch_bounds__(256) void k_part(const int* __restrict__ src,
                                              const int* __restrict__ dst,
                                              const int* __restrict__ hist,
                                              int* __restrict__ gcur,
                                              u32* __restrict__ pairs) {
  __shared__ int lbase[NB];
  __shared__ int lcur[NB];
  int tid = threadIdx.x, blk = blockIdx.x;
  for (int b = tid; b < NB; b += 256) {
    int c = hist[blk * NB + b];
    lbase[b] = c ? atomicAdd(&gcur[b], c) : 0;
    lcur[b] = 0;
  }
  __syncthreads();
  int e0 = blk * PER_BLK;
  int n = min(PER_BLK, N_EDGES - e0);            // multiple of 4
  const int4* s4 = (const int4*)(src + e0);
  const int4* d4 = (const int4*)(dst + e0);
  for (int i = tid; i < (n >> 2); i += 256) {
    int4 sv = s4[i];
    int4 dv = d4[i];
    { int b = dv.x >> 8; u32 v = ((u32)(dv.x & 255) << 17) | (u32)sv.x;
      pairs[lbase[b] + atomicAdd(&lcur[b], 1)] = v; }
    { int b = dv.y >> 8; u32 v = ((u32)(dv.y & 255) << 17) | (u32)sv.y;
      pairs[lbase[b] + atomicAdd(&lcur[b], 1)] = v; }
    { int b = dv.z >> 8; u32 v = ((u32)(dv.z & 255) << 17) | (u32)sv.z;
      pairs[lbase[b] + atomicAdd(&lcur[b], 1)] = v; }
    { int b = dv.w >> 8; u32 v = ((u32)(dv.w & 255) << 17) | (u32)sv.w;
      pairs[lbase[b] + atomicAdd(&lcur[b], 1)] = v; }
  }
}

// -------- GEMM1 via MFMA + LDS staging; writes h1p = bf16(dinv*h1) directly ----
__global__ __launch_bounds__(256) void k_gemm1(const float* __restrict__ x,
                                               const uint4* __restrict__ bfragG,
                                               const int* __restrict__ deg,
                                               unsigned short* __restrict__ h1p) {
  __shared__ __align__(16) char ldsbuf[2][64 * 80];   // 10 KB
  int tid = threadIdx.x;
  int blockRow0 = blockIdx.x * 64;

  // staging: thread covers rows r0 (=tid>>3) and r1 (=r0+32), slot s=tid&7
  int r0 = tid >> 3, r1 = r0 + 32, s = tid & 7;
  bool ok1 = (blockRow0 + r1) < N_NODES;
  const float* x0 = x + (size_t)(blockRow0 + r0) * F_IN + s * 4;
  const float* x1 = x + (size_t)(blockRow0 + r1) * F_IN + s * 4;

  int wv = tid >> 6, lane = tid & 63;
  int col = lane & 15, g = lane >> 4;
  int wid = blockIdx.x * 4 + wv;
  int fragRow = wv * 16 + col;

  f32x4 acc = {0.f, 0.f, 0.f, 0.f};

  {
    float4 fA = *(const float4*)(x0);
    float4 fB = ok1 ? *(const float4*)(x1) : make_float4(0.f, 0.f, 0.f, 0.f);
    uint2 qA = {cvt2(fA.x, fA.y), cvt2(fA.z, fA.w)};
    uint2 qB = {cvt2(fB.x, fB.y), cvt2(fB.z, fB.w)};
    *(uint2*)(&ldsbuf[0][r0 * 80 + s * 8]) = qA;
    *(uint2*)(&ldsbuf[0][r1 * 80 + s * 8]) = qB;
  }
  __syncthreads();

#pragma unroll
  for (int kk = 0; kk < 16; kk++) {
    int cur = kk & 1;
    float4 fA, fB;
    if (kk < 15) {
      fA = *(const float4*)(x0 + (kk + 1) * 32);
      fB = ok1 ? *(const float4*)(x1 + (kk + 1) * 32) : make_float4(0.f, 0.f, 0.f, 0.f);
    }
    FragU a, b;
    a.q = *(const uint4*)(&ldsbuf[cur][fragRow * 80 + g * 16]);
    b.q = bfragG[kk * 64 + lane];
    acc = __builtin_amdgcn_mfma_f32_16x16x32_bf16(a.v, b.v, acc, 0, 0, 0);
    if (kk < 15) {
      uint2 qA = {cvt2(fA.x, fA.y), cvt2(fA.z, fA.w)};
      uint2 qB = {cvt2(fB.x, fB.y), cvt2(fB.z, fB.w)};
      *(uint2*)(&ldsbuf[cur ^ 1][r0 * 80 + s * 8]) = qA;
      *(uint2*)(&ldsbuf[cur ^ 1][r1 * 80 + s * 8]) = qB;
    }
    __syncthreads();
  }

  // D: col = lane&15 (feature), row = (lane>>4)*4 + r; fold dinv, store bf16
#pragma unroll
  for (int r = 0; r < 4; r++) {
    int node = wid * 16 + g * 4 + r;
    if (node < N_NODES) {
      float di = rsqrtf((float)(deg[node] + 1));
      h1p[(size_t)node * F_H + col] = f2bf(di * acc[r]);
    }
  }
}

// ====== agg1: per-bucket group-in-LDS then node-parallel register reduce ======
// phases: int-hist -> scan -> scatter col[] -> 2 threads/node gather+reduce.
// No float atomics anywhere.
__global__ __launch_bounds__(512) void k_agg1(const u32* __restrict__ pairs,
                                              const int* __restrict__ pbase,
                                              const unsigned short* __restrict__ h1p,
                                              const float* __restrict__ b1,
                                              const float* __restrict__ W2,
                                              unsigned short* __restrict__ gfp) {
  __shared__ u32 col[CAPB];                      // 40 KB grouped src indices
  __shared__ int hist256[256];
  __shared__ int scan_[256];
  __shared__ int excl[256];
  __shared__ int cur[256];
  int tid = threadIdx.x, b = blockIdx.x;
  if (tid < 256) { hist256[tid] = 0; cur[tid] = 0; }
  __syncthreads();
  int base = pbase[b], cnt = pbase[b + 1] - base;
  for (int k = tid; k < cnt; k += 512)
    atomicAdd(&hist256[pairs[base + k] >> 17], 1);
  __syncthreads();
  if (tid < 256) scan_[tid] = hist256[tid];
  __syncthreads();
  for (int off = 1; off < 256; off <<= 1) {
    int v = 0;
    if (tid < 256 && tid >= off) v = scan_[tid - off];
    __syncthreads();
    if (tid < 256) scan_[tid] += v;
    __syncthreads();
  }
  if (tid < 256) excl[tid] = scan_[tid] - hist256[tid];
  __syncthreads();
  for (int k = tid; k < cnt; k += 512) {
    u32 v = pairs[base + k];
    int dl = v >> 17;
    col[excl[dl] + atomicAdd(&cur[dl], 1)] = v & 0x1FFFF;
  }
  __syncthreads();

  // node-parallel: thread pair (tid, tid^1) owns node b*256 + (tid>>1);
  // h = tid&1 selects which uint4 half-row (8 feats) this thread gathers.
  int dl = tid >> 1, h = tid & 1;
  int node = b * 256 + dl;
  if (node >= N_NODES) return;                   // whole waves exit together (160%32==0)
  int s0 = excl[dl], c0 = hist256[dl];
  const uint4* hp = (const uint4*)h1p;
  float a[8] = {0.f, 0.f, 0.f, 0.f, 0.f, 0.f, 0.f, 0.f};
  for (int e = s0; e < s0 + c0; e++) {
    uint4 hv = hp[col[e] * 2 + h];
    a[0] += bflo(hv.x); a[1] += bfhi(hv.x);
    a[2] += bflo(hv.y); a[3] += bfhi(hv.y);
    a[4] += bflo(hv.z); a[5] += bfhi(hv.z);
    a[6] += bflo(hv.w); a[7] += bfhi(hv.w);
  }
  {                                              // self-loop (dinv pre-folded)
    uint4 hv = hp[node * 2 + h];
    a[0] += bflo(hv.x); a[1] += bfhi(hv.x);
    a[2] += bflo(hv.y); a[3] += bfhi(hv.y);
    a[4] += bflo(hv.z); a[5] += bfhi(hv.z);
    a[6] += bflo(hv.w); a[7] += bfhi(hv.w);
  }
  float di = rsqrtf((float)(c0 + 1));
  float own[8];
#pragma unroll
  for (int k = 0; k < 8; k++)
    own[k] = fmaxf(di * a[k] + b1[h * 8 + k], 0.f);
  float oth[8];
#pragma unroll
  for (int k = 0; k < 8; k++) oth[k] = __shfl_xor(own[k], 1, 64);
  if (h == 0) {
    // own = feats 0..7, oth = feats 8..15
    float o[7] = {0.f, 0.f, 0.f, 0.f, 0.f, 0.f, 0.f};
#pragma unroll
    for (int k = 0; k < 8; k++)
#pragma unroll
      for (int j = 0; j < 7; j++)
        o[j] += own[k] * W2[k * 7 + j] + oth[k] * W2[(k + 8) * 7 + j];
    uint4 q;
    q.x = cvt2(di * o[0], di * o[1]);
    q.y = cvt2(di * o[2], di * o[3]);
    q.z = cvt2(di * o[4], di * o[5]);
    q.w = cvt2(di * o[6], 0.f);
    ((uint4*)gfp)[node] = q;
  }
}

// ====== agg2: same grouping; 2 threads/node split edges; softmax epilogue ======
__global__ __launch_bounds__(512) void k_agg2(const u32* __restrict__ pairs,
                                              const int* __restrict__ pbase,
                                              const unsigned short* __restrict__ gfp,
                                              const float* __restrict__ b2,
                                              float* __restrict__ out) {
  __shared__ u32 col[CAPB];
  __shared__ int hist256[256];
  __shared__ int scan_[256];
  __shared__ int excl[256];
  __shared__ int cur[256];
  int tid = threadIdx.x, b = blockIdx.x;
  if (tid < 256) { hist256[tid] = 0; cur[tid] = 0; }
  __syncthreads();
  int base = pbase[b], cnt = pbase[b + 1] - base;
  for (int k = tid; k < cnt; k += 512)
    atomicAdd(&hist256[pairs[base + k] >> 17], 1);
  __syncthreads();
  if (tid < 256) scan_[tid] = hist256[tid];
  __syncthreads();
  for (int off = 1; off < 256; off <<= 1) {
    int v = 0;
    if (tid < 256 && tid >= off) v = scan_[tid - off];
    __syncthreads();
    if (tid < 256) scan_[tid] += v;
    __syncthreads();
  }
  if (tid < 256) excl[tid] = scan_[tid] - hist256[tid];
  __syncthreads();
  for (int k = tid; k < cnt; k += 512) {
    u32 v = pairs[base + k];
    int dl = v >> 17;
    col[excl[dl] + atomicAdd(&cur[dl], 1)] = v & 0x1FFFF;
  }
  __syncthreads();

  int dl = tid >> 1, h = tid & 1;
  int node = b * 256 + dl;
  if (node >= N_NODES) return;
  int s0 = excl[dl], c0 = hist256[dl];
  const uint4* gp = (const uint4*)gfp;
  float a[7] = {0.f, 0.f, 0.f, 0.f, 0.f, 0.f, 0.f};
  for (int e = s0 + h; e < s0 + c0; e += 2) {    // edges split between the pair
    uint4 gv = gp[col[e]];
    a[0] += bflo(gv.x); a[1] += bfhi(gv.x);
    a[2] += bflo(gv.y); a[3] += bfhi(gv.y);
    a[4] += bflo(gv.z); a[5] += bfhi(gv.z);
    a[6] += bflo(gv.w);
  }
#pragma unroll
  for (int j = 0; j < 7; j++) a[j] += __shfl_xor(a[j], 1, 64);
  if (h == 0) {
    uint4 sv = gp[node];                         // self-loop
    a[0] += bflo(sv.x); a[1] += bfhi(sv.x);
    a[2] += bflo(sv.y); a[3] += bfhi(sv.y);
    a[4] += bflo(sv.z); a[5] += bfhi(sv.z);
    a[6] += bflo(sv.w);
    float di = rsqrtf((float)(c0 + 1));
    float v[7];
#pragma unroll
    for (int j = 0; j < 7; j++) v[j] = di * a[j] + b2[j];
    float m = v[0];
#pragma unroll
    for (int j = 1; j < 7; j++) m = fmaxf(m, v[j]);
    float s = 0.f;
#pragma unroll
    for (int j = 0; j < 7; j++) s += __expf(v[j] - m);
    float ls = m + logf(s);
#pragma unroll
    for (int j = 0; j < 7; j++) out[(size_t)node * 7 + j] = v[j] - ls;
  }
}

extern "C" void kernel_launch(void* const* d_in, const int* in_sizes, int n_in,
                              void* d_out, int out_size, void* d_ws, size_t ws_size,
                              hipStream_t stream) {
  const float* x  = (const float*)d_in[0];
  const int*   ei = (const int*)d_in[1];     // [0..E)=src, [E..2E)=dst (int32)
  const float* W1 = (const float*)d_in[2];
  const float* b1 = (const float*)d_in[3];
  const float* W2 = (const float*)d_in[4];
  const float* b2 = (const float*)d_in[5];
  float* out = (float*)d_out;

  // workspace layout (~18.8 MB; d_ws ~800 MB)
  char* base = (char*)d_ws;
  int*   bcnt   = (int*)(base + 0);            //      2,048
  int*   deg    = (int*)(base + 2048);         //    400,128   [memset covers bcnt+deg]
  int*   pbase  = (int*)(base + 402176);       //      2,048
  int*   gcur   = (int*)(base + 404224);       //      2,048
  uint4* bfragG = (uint4*)(base + 406272);     //     16,384
  int*   hist   = (int*)(base + 422656);       //    800,768 (GPART*NB*4)
  u32*   pairs  = (u32*)(base + 1223424);      // 12.8 MB  (ends 14,023,424)
  unsigned short* h1p = (unsigned short*)(base + 14023424); // 3.2 MB (ends 17,223,424)
  unsigned short* gfp = (unsigned short*)(base + 17223424); // 1.6 MB (ends 18,823,424)

  hipMemsetAsync(base, 0, 402176, stream);     // bcnt + deg

  k_hist    <<<GPART, 256, 0, stream>>>(ei + N_EDGES, hist, bcnt, deg);
  k_scanprep<<<2, 512, 0, stream>>>(bcnt, pbase, gcur, W1, bfragG);
  k_part    <<<GPART, 256, 0, stream>>>(ei, ei + N_EDGES, hist, gcur, pairs);
  k_gemm1   <<<(NTILES + 3) / 4, 256, 0, stream>>>(x, bfragG, deg, h1p);
  k_agg1    <<<NB, 512, 0, stream>>>(pairs, pbase, h1p, b1, W2, gfp);
  k_agg2    <<<NB, 512, 0, stream>>>(pairs, pbase, gfp, b2, out);
}

// Round 14
// 167.489 us; speedup vs baseline: 4.2470x; 1.6530x over previous
//
#include <hip/hip_runtime.h>
#include <hip/hip_bf16.h>

#define N_NODES 100000
#define N_EDGES 3200000
#define F_IN    512
#define F_H     16
#define F_OUT   7
#define NB      391                 // buckets of 256 dst nodes
#define GPART   512                 // partition blocks
#define PER_BLK 6256                // multiple of 4; 512*6256 >= 3.2M (last block short)
#define NTILES  6250                // 100000 / 16 row-tiles
#define CAPB    10240               // per-bucket edge cap (mean 8184, sigma~90 -> 22 sigma)

typedef unsigned int u32;
typedef __attribute__((ext_vector_type(8))) __bf16 bf16x8;
typedef __attribute__((ext_vector_type(4))) float f32x4;

union FragU { uint4 q; bf16x8 v; };

static __device__ __forceinline__ float bflo(u32 u) { return __uint_as_float(u << 16); }
static __device__ __forceinline__ float bfhi(u32 u) { return __uint_as_float(u & 0xFFFF0000u); }
static __device__ __forceinline__ unsigned short f2bf(float f) {
  u32 x = __float_as_uint(f);
  x += 0x7FFF + ((x >> 16) & 1);    // round-to-nearest-even (finite values)
  return (unsigned short)(x >> 16);
}
// pack two fp32 -> two bf16 in one u32 (low16 = a, high16 = b)
static __device__ __forceinline__ u32 cvt2(float a, float b) {
  u32 r;
  asm("v_cvt_pk_bf16_f32 %0, %1, %2" : "=v"(r) : "v"(a), "v"(b));
  return r;
}

// ------ bucket histogram (per-block rows + bucket totals); NO global deg ------
__global__ __launch_bounds__(256) void k_hist(const int* __restrict__ dst,
                                              int* __restrict__ hist,
                                              int* __restrict__ bcnt) {
  __shared__ int h[NB];
  int tid = threadIdx.x, blk = blockIdx.x;
  for (int b = tid; b < NB; b += 256) h[b] = 0;
  __syncthreads();
  int e0 = blk * PER_BLK;
  int n = min(PER_BLK, N_EDGES - e0);            // multiple of 4
  const int4* d4 = (const int4*)(dst + e0);
  for (int i = tid; i < (n >> 2); i += 256) {
    int4 d = d4[i];
    atomicAdd(&h[d.x >> 8], 1);
    atomicAdd(&h[d.y >> 8], 1);
    atomicAdd(&h[d.z >> 8], 1);
    atomicAdd(&h[d.w >> 8], 1);
  }
  __syncthreads();
  for (int b = tid; b < NB; b += 256) {
    int c = h[b];
    hist[blk * NB + b] = c;                      // block-major per-block counts
    if (c) atomicAdd(&bcnt[b], c);               // bucket totals
  }
}

// ---- grid=2: block 0 = bucket-base scan; block 1 = W1 bf16 B-fragment table ----
__global__ __launch_bounds__(512) void k_scanprep(const int* __restrict__ bcnt,
                                                  int* __restrict__ pbase,
                                                  int* __restrict__ gcur,
                                                  const float* __restrict__ W1,
                                                  uint4* __restrict__ bfragG) {
  int tid = threadIdx.x;
  if (blockIdx.x == 1) {
    // B-fragment for mfma_f32_16x16x32_bf16: lane l holds B[k=(l>>4)*8+j][col=l&15]
    for (int idx = tid; idx < 1024; idx += 512) {  // 16 kk * 64 lanes
      int kk = idx >> 6, lane = idx & 63;
      int col = lane & 15, g = lane >> 4;
      int k0 = kk * 32 + g * 8;
      uint4 q;
      q.x = cvt2(W1[(k0 + 0) * 16 + col], W1[(k0 + 1) * 16 + col]);
      q.y = cvt2(W1[(k0 + 2) * 16 + col], W1[(k0 + 3) * 16 + col]);
      q.z = cvt2(W1[(k0 + 4) * 16 + col], W1[(k0 + 5) * 16 + col]);
      q.w = cvt2(W1[(k0 + 6) * 16 + col], W1[(k0 + 7) * 16 + col]);
      bfragG[idx] = q;
    }
    return;
  }
  __shared__ int lds[512];
  int c = (tid < NB) ? bcnt[tid] : 0;
  lds[tid] = c;
  __syncthreads();
  for (int off = 1; off < 512; off <<= 1) {
    int v = (tid >= off) ? lds[tid - off] : 0;
    __syncthreads();
    lds[tid] += v;
    __syncthreads();
  }
  int ex = lds[tid] - c;
  if (tid <= NB) pbase[tid] = ex;     // pbase[NB] == N_EDGES (total)
  if (tid < NB) gcur[tid] = ex;
}

// -------- partition scatter: reserve ranges atomically, LDS cursors --------
// pack: (dst_local << 17) | src
__global__ __launch_bounds__(256) void k_part(const int* __restrict__ src,
                                              const int* __restrict__ dst,
                                              const int* __restrict__ hist,
                                              int* __restrict__ gcur,
                                              u32* __restrict__ pairs) {
  __shared__ int lbase[NB];
  __shared__ int lcur[NB];
  int tid = threadIdx.x, blk = blockIdx.x;
  for (int b = tid; b < NB; b += 256) {
    int c = hist[blk * NB + b];
    lbase[b] = c ? atomicAdd(&gcur[b], c) : 0;
    lcur[b] = 0;
  }
  __syncthreads();
  int e0 = blk * PER_BLK;
  int n = min(PER_BLK, N_EDGES - e0);            // multiple of 4
  const int4* s4 = (const int4*)(src + e0);
  const int4* d4 = (const int4*)(dst + e0);
  for (int i = tid; i < (n >> 2); i += 256) {
    int4 sv = s4[i];
    int4 dv = d4[i];
    { int b = dv.x >> 8; u32 v = ((u32)(dv.x & 255) << 17) | (u32)sv.x;
      pairs[lbase[b] + atomicAdd(&lcur[b], 1)] = v; }
    { int b = dv.y >> 8; u32 v = ((u32)(dv.y & 255) << 17) | (u32)sv.y;
      pairs[lbase[b] + atomicAdd(&lcur[b], 1)] = v; }
    { int b = dv.z >> 8; u32 v = ((u32)(dv.z & 255) << 17) | (u32)sv.z;
      pairs[lbase[b] + atomicAdd(&lcur[b], 1)] = v; }
    { int b = dv.w >> 8; u32 v = ((u32)(dv.w & 255) << 17) | (u32)sv.w;
      pairs[lbase[b] + atomicAdd(&lcur[b], 1)] = v; }
  }
}

// ------ per-bucket degree from pairs (int LDS hist, coalesced deg write) ------
__global__ __launch_bounds__(256) void k_deg(const u32* __restrict__ pairs,
                                             const int* __restrict__ pbase,
                                             int* __restrict__ deg) {
  __shared__ int h[256];
  int tid = threadIdx.x, b = blockIdx.x;
  h[tid] = 0;
  __syncthreads();
  int base = pbase[b], cnt = pbase[b + 1] - base;
  for (int k = tid; k < cnt; k += 256)
    atomicAdd(&h[pairs[base + k] >> 17], 1);
  __syncthreads();
  int node = b * 256 + tid;
  if (node < N_NODES) deg[node] = h[tid];
}

// -------- GEMM1 via MFMA + LDS staging; writes h1p = bf16(dinv*h1) directly ----
__global__ __launch_bounds__(256) void k_gemm1(const float* __restrict__ x,
                                               const uint4* __restrict__ bfragG,
                                               const int* __restrict__ deg,
                                               unsigned short* __restrict__ h1p) {
  __shared__ __align__(16) char ldsbuf[2][64 * 80];   // 10 KB
  int tid = threadIdx.x;
  int blockRow0 = blockIdx.x * 64;

  // staging: thread covers rows r0 (=tid>>3) and r1 (=r0+32), slot s=tid&7
  int r0 = tid >> 3, r1 = r0 + 32, s = tid & 7;
  bool ok1 = (blockRow0 + r1) < N_NODES;
  const float* x0 = x + (size_t)(blockRow0 + r0) * F_IN + s * 4;
  const float* x1 = x + (size_t)(blockRow0 + r1) * F_IN + s * 4;

  int wv = tid >> 6, lane = tid & 63;
  int col = lane & 15, g = lane >> 4;
  int wid = blockIdx.x * 4 + wv;
  int fragRow = wv * 16 + col;

  f32x4 acc = {0.f, 0.f, 0.f, 0.f};

  {
    float4 fA = *(const float4*)(x0);
    float4 fB = ok1 ? *(const float4*)(x1) : make_float4(0.f, 0.f, 0.f, 0.f);
    uint2 qA = {cvt2(fA.x, fA.y), cvt2(fA.z, fA.w)};
    uint2 qB = {cvt2(fB.x, fB.y), cvt2(fB.z, fB.w)};
    *(uint2*)(&ldsbuf[0][r0 * 80 + s * 8]) = qA;
    *(uint2*)(&ldsbuf[0][r1 * 80 + s * 8]) = qB;
  }
  __syncthreads();

#pragma unroll
  for (int kk = 0; kk < 16; kk++) {
    int cur = kk & 1;
    float4 fA, fB;
    if (kk < 15) {
      fA = *(const float4*)(x0 + (kk + 1) * 32);
      fB = ok1 ? *(const float4*)(x1 + (kk + 1) * 32) : make_float4(0.f, 0.f, 0.f, 0.f);
    }
    FragU a, b;
    a.q = *(const uint4*)(&ldsbuf[cur][fragRow * 80 + g * 16]);
    b.q = bfragG[kk * 64 + lane];
    acc = __builtin_amdgcn_mfma_f32_16x16x32_bf16(a.v, b.v, acc, 0, 0, 0);
    if (kk < 15) {
      uint2 qA = {cvt2(fA.x, fA.y), cvt2(fA.z, fA.w)};
      uint2 qB = {cvt2(fB.x, fB.y), cvt2(fB.z, fB.w)};
      *(uint2*)(&ldsbuf[cur ^ 1][r0 * 80 + s * 8]) = qA;
      *(uint2*)(&ldsbuf[cur ^ 1][r1 * 80 + s * 8]) = qB;
    }
    __syncthreads();
  }

  // D: col = lane&15 (feature), row = (lane>>4)*4 + r; fold dinv, store bf16
#pragma unroll
  for (int r = 0; r < 4; r++) {
    int node = wid * 16 + g * 4 + r;
    if (node < N_NODES) {
      float di = rsqrtf((float)(deg[node] + 1));
      h1p[(size_t)node * F_H + col] = f2bf(di * acc[r]);
    }
  }
}

// ====== agg1: per-bucket group-in-LDS then node-parallel register reduce ======
// phases: int-hist -> scan -> scatter col[] -> 2 threads/node gather+reduce.
// No float atomics anywhere.
__global__ __launch_bounds__(512) void k_agg1(const u32* __restrict__ pairs,
                                              const int* __restrict__ pbase,
                                              const unsigned short* __restrict__ h1p,
                                              const float* __restrict__ b1,
                                              const float* __restrict__ W2,
                                              unsigned short* __restrict__ gfp) {
  __shared__ u32 col[CAPB];                      // 40 KB grouped src indices
  __shared__ int hist256[256];
  __shared__ int scan_[256];
  __shared__ int excl[256];
  __shared__ int cur[256];
  int tid = threadIdx.x, b = blockIdx.x;
  if (tid < 256) { hist256[tid] = 0; cur[tid] = 0; }
  __syncthreads();
  int base = pbase[b], cnt = pbase[b + 1] - base;
  for (int k = tid; k < cnt; k += 512)
    atomicAdd(&hist256[pairs[base + k] >> 17], 1);
  __syncthreads();
  if (tid < 256) scan_[tid] = hist256[tid];
  __syncthreads();
  for (int off = 1; off < 256; off <<= 1) {
    int v = 0;
    if (tid < 256 && tid >= off) v = scan_[tid - off];
    __syncthreads();
    if (tid < 256) scan_[tid] += v;
    __syncthreads();
  }
  if (tid < 256) excl[tid] = scan_[tid] - hist256[tid];
  __syncthreads();
  for (int k = tid; k < cnt; k += 512) {
    u32 v = pairs[base + k];
    int dl = v >> 17;
    col[excl[dl] + atomicAdd(&cur[dl], 1)] = v & 0x1FFFF;
  }
  __syncthreads();

  // node-parallel: thread pair (tid, tid^1) owns node b*256 + (tid>>1);
  // h = tid&1 selects which uint4 half-row (8 feats) this thread gathers.
  int dl = tid >> 1, h = tid & 1;
  int node = b * 256 + dl;
  if (node >= N_NODES) return;                   // whole waves exit together (160%32==0)
  int s0 = excl[dl], c0 = hist256[dl];
  const uint4* hp = (const uint4*)h1p;
  float a[8] = {0.f, 0.f, 0.f, 0.f, 0.f, 0.f, 0.f, 0.f};
  for (int e = s0; e < s0 + c0; e++) {
    uint4 hv = hp[col[e] * 2 + h];
    a[0] += bflo(hv.x); a[1] += bfhi(hv.x);
    a[2] += bflo(hv.y); a[3] += bfhi(hv.y);
    a[4] += bflo(hv.z); a[5] += bfhi(hv.z);
    a[6] += bflo(hv.w); a[7] += bfhi(hv.w);
  }
  {                                              // self-loop (dinv pre-folded)
    uint4 hv = hp[node * 2 + h];
    a[0] += bflo(hv.x); a[1] += bfhi(hv.x);
    a[2] += bflo(hv.y); a[3] += bfhi(hv.y);
    a[4] += bflo(hv.z); a[5] += bfhi(hv.z);
    a[6] += bflo(hv.w); a[7] += bfhi(hv.w);
  }
  float di = rsqrtf((float)(c0 + 1));
  float own[8];
#pragma unroll
  for (int k = 0; k < 8; k++)
    own[k] = fmaxf(di * a[k] + b1[h * 8 + k], 0.f);
  float oth[8];
#pragma unroll
  for (int k = 0; k < 8; k++) oth[k] = __shfl_xor(own[k], 1, 64);
  if (h == 0) {
    // own = feats 0..7, oth = feats 8..15
    float o[7] = {0.f, 0.f, 0.f, 0.f, 0.f, 0.f, 0.f};
#pragma unroll
    for (int k = 0; k < 8; k++)
#pragma unroll
      for (int j = 0; j < 7; j++)
        o[j] += own[k] * W2[k * 7 + j] + oth[k] * W2[(k + 8) * 7 + j];
    uint4 q;
    q.x = cvt2(di * o[0], di * o[1]);
    q.y = cvt2(di * o[2], di * o[3]);
    q.z = cvt2(di * o[4], di * o[5]);
    q.w = cvt2(di * o[6], 0.f);
    ((uint4*)gfp)[node] = q;
  }
}

// ====== agg2: same grouping; 2 threads/node split edges; softmax epilogue ======
__global__ __launch_bounds__(512) void k_agg2(const u32* __restrict__ pairs,
                                              const int* __restrict__ pbase,
                                              const unsigned short* __restrict__ gfp,
                                              const float* __restrict__ b2,
                                              float* __restrict__ out) {
  __shared__ u32 col[CAPB];
  __shared__ int hist256[256];
  __shared__ int scan_[256];
  __shared__ int excl[256];
  __shared__ int cur[256];
  int tid = threadIdx.x, b = blockIdx.x;
  if (tid < 256) { hist256[tid] = 0; cur[tid] = 0; }
  __syncthreads();
  int base = pbase[b], cnt = pbase[b + 1] - base;
  for (int k = tid; k < cnt; k += 512)
    atomicAdd(&hist256[pairs[base + k] >> 17], 1);
  __syncthreads();
  if (tid < 256) scan_[tid] = hist256[tid];
  __syncthreads();
  for (int off = 1; off < 256; off <<= 1) {
    int v = 0;
    if (tid < 256 && tid >= off) v = scan_[tid - off];
    __syncthreads();
    if (tid < 256) scan_[tid] += v;
    __syncthreads();
  }
  if (tid < 256) excl[tid] = scan_[tid] - hist256[tid];
  __syncthreads();
  for (int k = tid; k < cnt; k += 512) {
    u32 v = pairs[base + k];
    int dl = v >> 17;
    col[excl[dl] + atomicAdd(&cur[dl], 1)] = v & 0x1FFFF;
  }
  __syncthreads();

  int dl = tid >> 1, h = tid & 1;
  int node = b * 256 + dl;
  if (node >= N_NODES) return;
  int s0 = excl[dl], c0 = hist256[dl];
  const uint4* gp = (const uint4*)gfp;
  float a[7] = {0.f, 0.f, 0.f, 0.f, 0.f, 0.f, 0.f};
  for (int e = s0 + h; e < s0 + c0; e += 2) {    // edges split between the pair
    uint4 gv = gp[col[e]];
    a[0] += bflo(gv.x); a[1] += bfhi(gv.x);
    a[2] += bflo(gv.y); a[3] += bfhi(gv.y);
    a[4] += bflo(gv.z); a[5] += bfhi(gv.z);
    a[6] += bflo(gv.w);
  }
#pragma unroll
  for (int j = 0; j < 7; j++) a[j] += __shfl_xor(a[j], 1, 64);
  if (h == 0) {
    uint4 sv = gp[node];                         // self-loop
    a[0] += bflo(sv.x); a[1] += bfhi(sv.x);
    a[2] += bflo(sv.y); a[3] += bfhi(sv.y);
    a[4] += bflo(sv.z); a[5] += bfhi(sv.z);
    a[6] += bflo(sv.w);
    float di = rsqrtf((float)(c0 + 1));
    float v[7];
#pragma unroll
    for (int j = 0; j < 7; j++) v[j] = di * a[j] + b2[j];
    float m = v[0];
#pragma unroll
    for (int j = 1; j < 7; j++) m = fmaxf(m, v[j]);
    float s = 0.f;
#pragma unroll
    for (int j = 0; j < 7; j++) s += __expf(v[j] - m);
    float ls = m + logf(s);
#pragma unroll
    for (int j = 0; j < 7; j++) out[(size_t)node * 7 + j] = v[j] - ls;
  }
}

extern "C" void kernel_launch(void* const* d_in, const int* in_sizes, int n_in,
                              void* d_out, int out_size, void* d_ws, size_t ws_size,
                              hipStream_t stream) {
  const float* x  = (const float*)d_in[0];
  const int*   ei = (const int*)d_in[1];     // [0..E)=src, [E..2E)=dst (int32)
  const float* W1 = (const float*)d_in[2];
  const float* b1 = (const float*)d_in[3];
  const float* W2 = (const float*)d_in[4];
  const float* b2 = (const float*)d_in[5];
  float* out = (float*)d_out;

  // workspace layout (~18.8 MB; d_ws ~800 MB)
  char* base = (char*)d_ws;
  int*   bcnt   = (int*)(base + 0);            //      2,048
  int*   deg    = (int*)(base + 2048);         //    400,128
  int*   pbase  = (int*)(base + 402176);       //      2,048
  int*   gcur   = (int*)(base + 404224);       //      2,048
  uint4* bfragG = (uint4*)(base + 406272);     //     16,384
  int*   hist   = (int*)(base + 422656);       //    800,768 (GPART*NB*4)
  u32*   pairs  = (u32*)(base + 1223424);      // 12.8 MB  (ends 14,023,424)
  unsigned short* h1p = (unsigned short*)(base + 14023424); // 3.2 MB (ends 17,223,424)
  unsigned short* gfp = (unsigned short*)(base + 17223424); // 1.6 MB (ends 18,823,424)

  hipMemsetAsync(bcnt, 0, 2048, stream);       // bcnt only (deg written by k_deg)

  k_hist    <<<GPART, 256, 0, stream>>>(ei + N_EDGES, hist, bcnt);
  k_scanprep<<<2, 512, 0, stream>>>(bcnt, pbase, gcur, W1, bfragG);
  k_part    <<<GPART, 256, 0, stream>>>(ei, ei + N_EDGES, hist, gcur, pairs);
  k_deg     <<<NB, 256, 0, stream>>>(pairs, pbase, deg);
  k_gemm1   <<<(NTILES + 3) / 4, 256, 0, stream>>>(x, bfragG, deg, h1p);
  k_agg1    <<<NB, 512, 0, stream>>>(pairs, pbase, h1p, b1, W2, gfp);
  k_agg2    <<<NB, 512, 0, stream>>>(pairs, pbase, gfp, b2, out);
}

// Round 15
// 137.744 us; speedup vs baseline: 5.1641x; 1.2159x over previous
//
#include <hip/hip_runtime.h>
#include <hip/hip_bf16.h>

#define N_NODES 100000
#define N_EDGES 3200000
#define F_IN    512
#define F_H     16
#define F_OUT   7
#define NB      391                 // buckets of 256 dst nodes
#define GPART   512                 // partition blocks
#define PER_BLK 6256                // multiple of 4; 512*6256 >= 3.2M (last block short)
#define NTILES  6250                // 100000 / 16 row-tiles
#define CAPB    10240               // fixed slot per bucket (mean 8184, sigma~90 -> 22 sigma)
#define NPAD    (NB * 256)          // 100096 padded node count

typedef unsigned int u32;
typedef __attribute__((ext_vector_type(8))) __bf16 bf16x8;
typedef __attribute__((ext_vector_type(4))) float f32x4;

union FragU { uint4 q; bf16x8 v; };

static __device__ __forceinline__ float bflo(u32 u) { return __uint_as_float(u << 16); }
static __device__ __forceinline__ float bfhi(u32 u) { return __uint_as_float(u & 0xFFFF0000u); }
static __device__ __forceinline__ unsigned short f2bf(float f) {
  u32 x = __float_as_uint(f);
  x += 0x7FFF + ((x >> 16) & 1);    // round-to-nearest-even (finite values)
  return (unsigned short)(x >> 16);
}
// pack two fp32 -> two bf16 in one u32 (low16 = a, high16 = b)
static __device__ __forceinline__ u32 cvt2(float a, float b) {
  u32 r;
  asm("v_cvt_pk_bf16_f32 %0, %1, %2" : "=v"(r) : "v"(a), "v"(b));
  return r;
}

// ---- prep (1 block): gcur[b] = b*CAPB  +  W1 bf16 B-fragment table ----
__global__ __launch_bounds__(512) void k_prep(int* __restrict__ gcur,
                                              const float* __restrict__ W1,
                                              uint4* __restrict__ bfragG) {
  int tid = threadIdx.x;
  if (tid < NB) gcur[tid] = tid * CAPB;
  // B-fragment for mfma_f32_16x16x32_bf16: lane l holds B[k=(l>>4)*8+j][col=l&15]
  for (int idx = tid; idx < 1024; idx += 512) {  // 16 kk * 64 lanes
    int kk = idx >> 6, lane = idx & 63;
    int col = lane & 15, g = lane >> 4;
    int k0 = kk * 32 + g * 8;
    uint4 q;
    q.x = cvt2(W1[(k0 + 0) * 16 + col], W1[(k0 + 1) * 16 + col]);
    q.y = cvt2(W1[(k0 + 2) * 16 + col], W1[(k0 + 3) * 16 + col]);
    q.z = cvt2(W1[(k0 + 4) * 16 + col], W1[(k0 + 5) * 16 + col]);
    q.w = cvt2(W1[(k0 + 6) * 16 + col], W1[(k0 + 7) * 16 + col]);
    bfragG[idx] = q;
  }
}

// ---- fused hist+partition: LDS hist -> atomic range reserve -> scatter ----
// pack: (dst_local << 17) | src
__global__ __launch_bounds__(256) void k_part(const int* __restrict__ src,
                                              const int* __restrict__ dst,
                                              int* __restrict__ gcur,
                                              u32* __restrict__ pairs) {
  __shared__ int h[NB];
  __shared__ int lbase[NB];
  __shared__ int lcur[NB];
  int tid = threadIdx.x, blk = blockIdx.x;
  for (int b = tid; b < NB; b += 256) h[b] = 0;
  __syncthreads();
  int e0 = blk * PER_BLK;
  int n = min(PER_BLK, N_EDGES - e0);            // multiple of 4
  const int4* s4 = (const int4*)(src + e0);
  const int4* d4 = (const int4*)(dst + e0);
  // pass 1: bucket histogram of this block's dsts
  for (int i = tid; i < (n >> 2); i += 256) {
    int4 d = d4[i];
    atomicAdd(&h[d.x >> 8], 1);
    atomicAdd(&h[d.y >> 8], 1);
    atomicAdd(&h[d.z >> 8], 1);
    atomicAdd(&h[d.w >> 8], 1);
  }
  __syncthreads();
  // reserve contiguous ranges in each bucket's fixed slot
  for (int b = tid; b < NB; b += 256) {
    int c = h[b];
    lbase[b] = c ? atomicAdd(&gcur[b], c) : 0;
    lcur[b] = 0;
  }
  __syncthreads();
  // pass 2: scatter (dst/src re-reads are L1/L2-hot)
  for (int i = tid; i < (n >> 2); i += 256) {
    int4 sv = s4[i];
    int4 dv = d4[i];
    { int b = dv.x >> 8; u32 v = ((u32)(dv.x & 255) << 17) | (u32)sv.x;
      pairs[lbase[b] + atomicAdd(&lcur[b], 1)] = v; }
    { int b = dv.y >> 8; u32 v = ((u32)(dv.y & 255) << 17) | (u32)sv.y;
      pairs[lbase[b] + atomicAdd(&lcur[b], 1)] = v; }
    { int b = dv.z >> 8; u32 v = ((u32)(dv.z & 255) << 17) | (u32)sv.z;
      pairs[lbase[b] + atomicAdd(&lcur[b], 1)] = v; }
    { int b = dv.w >> 8; u32 v = ((u32)(dv.w & 255) << 17) | (u32)sv.w;
      pairs[lbase[b] + atomicAdd(&lcur[b], 1)] = v; }
  }
}

// ---- per-bucket degree + exclusive scan from pairs (coalesced writes) ----
__global__ __launch_bounds__(256) void k_deg(const u32* __restrict__ pairs,
                                             const int* __restrict__ gcur,
                                             int* __restrict__ dega,
                                             int* __restrict__ excla) {
  __shared__ int h[256];
  __shared__ int sc[256];
  int tid = threadIdx.x, b = blockIdx.x;
  h[tid] = 0;
  __syncthreads();
  int base = b * CAPB;
  int cnt = gcur[b] - base;
  for (int k = tid; k < cnt; k += 256)
    atomicAdd(&h[pairs[base + k] >> 17], 1);
  __syncthreads();
  int c = h[tid];
  sc[tid] = c;
  __syncthreads();
  for (int off = 1; off < 256; off <<= 1) {
    int v = (tid >= off) ? sc[tid - off] : 0;
    __syncthreads();
    sc[tid] += v;
    __syncthreads();
  }
  int node = b * 256 + tid;
  dega[node] = c;
  excla[node] = sc[tid] - c;
}

// -------- GEMM1 via MFMA + LDS staging; writes h1p = bf16(dinv*h1) directly ----
__global__ __launch_bounds__(256) void k_gemm1(const float* __restrict__ x,
                                               const uint4* __restrict__ bfragG,
                                               const int* __restrict__ dega,
                                               unsigned short* __restrict__ h1p) {
  __shared__ __align__(16) char ldsbuf[2][64 * 80];   // 10 KB
  int tid = threadIdx.x;
  int blockRow0 = blockIdx.x * 64;

  // staging: thread covers rows r0 (=tid>>3) and r1 (=r0+32), slot s=tid&7
  int r0 = tid >> 3, r1 = r0 + 32, s = tid & 7;
  bool ok1 = (blockRow0 + r1) < N_NODES;
  const float* x0 = x + (size_t)(blockRow0 + r0) * F_IN + s * 4;
  const float* x1 = x + (size_t)(blockRow0 + r1) * F_IN + s * 4;

  int wv = tid >> 6, lane = tid & 63;
  int col = lane & 15, g = lane >> 4;
  int wid = blockIdx.x * 4 + wv;
  int fragRow = wv * 16 + col;

  f32x4 acc = {0.f, 0.f, 0.f, 0.f};

  {
    float4 fA = *(const float4*)(x0);
    float4 fB = ok1 ? *(const float4*)(x1) : make_float4(0.f, 0.f, 0.f, 0.f);
    uint2 qA = {cvt2(fA.x, fA.y), cvt2(fA.z, fA.w)};
    uint2 qB = {cvt2(fB.x, fB.y), cvt2(fB.z, fB.w)};
    *(uint2*)(&ldsbuf[0][r0 * 80 + s * 8]) = qA;
    *(uint2*)(&ldsbuf[0][r1 * 80 + s * 8]) = qB;
  }
  __syncthreads();

#pragma unroll
  for (int kk = 0; kk < 16; kk++) {
    int cur = kk & 1;
    float4 fA, fB;
    if (kk < 15) {
      fA = *(const float4*)(x0 + (kk + 1) * 32);
      fB = ok1 ? *(const float4*)(x1 + (kk + 1) * 32) : make_float4(0.f, 0.f, 0.f, 0.f);
    }
    FragU a, b;
    a.q = *(const uint4*)(&ldsbuf[cur][fragRow * 80 + g * 16]);
    b.q = bfragG[kk * 64 + lane];
    acc = __builtin_amdgcn_mfma_f32_16x16x32_bf16(a.v, b.v, acc, 0, 0, 0);
    if (kk < 15) {
      uint2 qA = {cvt2(fA.x, fA.y), cvt2(fA.z, fA.w)};
      uint2 qB = {cvt2(fB.x, fB.y), cvt2(fB.z, fB.w)};
      *(uint2*)(&ldsbuf[cur ^ 1][r0 * 80 + s * 8]) = qA;
      *(uint2*)(&ldsbuf[cur ^ 1][r1 * 80 + s * 8]) = qB;
    }
    __syncthreads();
  }

  // D: col = lane&15 (feature), row = (lane>>4)*4 + r; fold dinv, store bf16
#pragma unroll
  for (int r = 0; r < 4; r++) {
    int node = wid * 16 + g * 4 + r;
    if (node < N_NODES) {
      float di = rsqrtf((float)(dega[node] + 1));
      h1p[(size_t)node * F_H + col] = f2bf(di * acc[r]);
    }
  }
}

// ====== agg1: scatter col[] (excl precomputed) + node-parallel reduce ======
__global__ __launch_bounds__(512) void k_agg1(const u32* __restrict__ pairs,
                                              const int* __restrict__ gcur,
                                              const int* __restrict__ dega,
                                              const int* __restrict__ excla,
                                              const unsigned short* __restrict__ h1p,
                                              const float* __restrict__ b1,
                                              const float* __restrict__ W2,
                                              unsigned short* __restrict__ gfp) {
  __shared__ u32 col[CAPB];                      // 40 KB grouped src indices
  __shared__ int exc[256];
  __shared__ int dg[256];
  __shared__ int cur[256];
  int tid = threadIdx.x, b = blockIdx.x;
  if (tid < 256) {
    int node = b * 256 + tid;
    dg[tid] = dega[node];
    exc[tid] = excla[node];
    cur[tid] = 0;
  }
  __syncthreads();
  int base = b * CAPB;
  int cnt = gcur[b] - base;
  for (int k = tid; k < cnt; k += 512) {
    u32 v = pairs[base + k];
    int dl = v >> 17;
    col[exc[dl] + atomicAdd(&cur[dl], 1)] = v & 0x1FFFF;
  }
  __syncthreads();

  // node-parallel: thread pair (tid, tid^1) owns node b*256 + (tid>>1);
  // h = tid&1 selects which uint4 half-row (8 feats) this thread gathers.
  int dl = tid >> 1, h = tid & 1;
  int node = b * 256 + dl;
  if (node >= N_NODES) return;                   // whole waves exit together
  int s0 = exc[dl], c0 = dg[dl];
  const uint4* hp = (const uint4*)h1p;
  float a[8] = {0.f, 0.f, 0.f, 0.f, 0.f, 0.f, 0.f, 0.f};
  for (int e = s0; e < s0 + c0; e++) {
    uint4 hv = hp[col[e] * 2 + h];
    a[0] += bflo(hv.x); a[1] += bfhi(hv.x);
    a[2] += bflo(hv.y); a[3] += bfhi(hv.y);
    a[4] += bflo(hv.z); a[5] += bfhi(hv.z);
    a[6] += bflo(hv.w); a[7] += bfhi(hv.w);
  }
  {                                              // self-loop (dinv pre-folded)
    uint4 hv = hp[node * 2 + h];
    a[0] += bflo(hv.x); a[1] += bfhi(hv.x);
    a[2] += bflo(hv.y); a[3] += bfhi(hv.y);
    a[4] += bflo(hv.z); a[5] += bfhi(hv.z);
    a[6] += bflo(hv.w); a[7] += bfhi(hv.w);
  }
  float di = rsqrtf((float)(c0 + 1));
  float own[8];
#pragma unroll
  for (int k = 0; k < 8; k++)
    own[k] = fmaxf(di * a[k] + b1[h * 8 + k], 0.f);
  float oth[8];
#pragma unroll
  for (int k = 0; k < 8; k++) oth[k] = __shfl_xor(own[k], 1, 64);
  if (h == 0) {
    // own = feats 0..7, oth = feats 8..15
    float o[7] = {0.f, 0.f, 0.f, 0.f, 0.f, 0.f, 0.f};
#pragma unroll
    for (int k = 0; k < 8; k++)
#pragma unroll
      for (int j = 0; j < 7; j++)
        o[j] += own[k] * W2[k * 7 + j] + oth[k] * W2[(k + 8) * 7 + j];
    uint4 q;
    q.x = cvt2(di * o[0], di * o[1]);
    q.y = cvt2(di * o[2], di * o[3]);
    q.z = cvt2(di * o[4], di * o[5]);
    q.w = cvt2(di * o[6], 0.f);
    ((uint4*)gfp)[node] = q;
  }
}

// ====== agg2: scatter col[] + 2-thr/node edge-split + softmax epilogue ======
__global__ __launch_bounds__(512) void k_agg2(const u32* __restrict__ pairs,
                                              const int* __restrict__ gcur,
                                              const int* __restrict__ dega,
                                              const int* __restrict__ excla,
                                              const unsigned short* __restrict__ gfp,
                                              const float* __restrict__ b2,
                                              float* __restrict__ out) {
  __shared__ u32 col[CAPB];
  __shared__ int exc[256];
  __shared__ int dg[256];
  __shared__ int cur[256];
  int tid = threadIdx.x, b = blockIdx.x;
  if (tid < 256) {
    int node = b * 256 + tid;
    dg[tid] = dega[node];
    exc[tid] = excla[node];
    cur[tid] = 0;
  }
  __syncthreads();
  int base = b * CAPB;
  int cnt = gcur[b] - base;
  for (int k = tid; k < cnt; k += 512) {
    u32 v = pairs[base + k];
    int dl = v >> 17;
    col[exc[dl] + atomicAdd(&cur[dl], 1)] = v & 0x1FFFF;
  }
  __syncthreads();

  int dl = tid >> 1, h = tid & 1;
  int node = b * 256 + dl;
  if (node >= N_NODES) return;
  int s0 = exc[dl], c0 = dg[dl];
  const uint4* gp = (const uint4*)gfp;
  float a[7] = {0.f, 0.f, 0.f, 0.f, 0.f, 0.f, 0.f};
  for (int e = s0 + h; e < s0 + c0; e += 2) {    // edges split between the pair
    uint4 gv = gp[col[e]];
    a[0] += bflo(gv.x); a[1] += bfhi(gv.x);
    a[2] += bflo(gv.y); a[3] += bfhi(gv.y);
    a[4] += bflo(gv.z); a[5] += bfhi(gv.z);
    a[6] += bflo(gv.w);
  }
#pragma unroll
  for (int j = 0; j < 7; j++) a[j] += __shfl_xor(a[j], 1, 64);
  if (h == 0) {
    uint4 sv = gp[node];                         // self-loop
    a[0] += bflo(sv.x); a[1] += bfhi(sv.x);
    a[2] += bflo(sv.y); a[3] += bfhi(sv.y);
    a[4] += bflo(sv.z); a[5] += bfhi(sv.z);
    a[6] += bflo(sv.w);
    float di = rsqrtf((float)(c0 + 1));
    float v[7];
#pragma unroll
    for (int j = 0; j < 7; j++) v[j] = di * a[j] + b2[j];
    float m = v[0];
#pragma unroll
    for (int j = 1; j < 7; j++) m = fmaxf(m, v[j]);
    float s = 0.f;
#pragma unroll
    for (int j = 0; j < 7; j++) s += __expf(v[j] - m);
    float ls = m + logf(s);
#pragma unroll
    for (int j = 0; j < 7; j++) out[(size_t)node * 7 + j] = v[j] - ls;
  }
}

extern "C" void kernel_launch(void* const* d_in, const int* in_sizes, int n_in,
                              void* d_out, int out_size, void* d_ws, size_t ws_size,
                              hipStream_t stream) {
  const float* x  = (const float*)d_in[0];
  const int*   ei = (const int*)d_in[1];     // [0..E)=src, [E..2E)=dst (int32)
  const float* W1 = (const float*)d_in[2];
  const float* b1 = (const float*)d_in[3];
  const float* W2 = (const float*)d_in[4];
  const float* b2 = (const float*)d_in[5];
  float* out = (float*)d_out;

  // workspace layout (~21.7 MB; d_ws ~800 MB)
  char* base = (char*)d_ws;
  int*   gcur   = (int*)(base + 0);            //      2,048
  uint4* bfragG = (uint4*)(base + 2048);       //     16,384
  int*   dega   = (int*)(base + 18432);        //    400,384 (NPAD*4)
  int*   excla  = (int*)(base + 418816);       //    400,384
  u32*   pairs  = (u32*)(base + 819200);       // 16,015,360 (NB*CAPB*4; ends 16,834,560)
  unsigned short* h1p = (unsigned short*)(base + 16834560); // 3.2 MB (ends 20,034,560)
  unsigned short* gfp = (unsigned short*)(base + 20034560); // 1.6 MB (ends 21,634,560)

  k_prep <<<1, 512, 0, stream>>>(gcur, W1, bfragG);
  k_part <<<GPART, 256, 0, stream>>>(ei, ei + N_EDGES, gcur, pairs);
  k_deg  <<<NB, 256, 0, stream>>>(pairs, gcur, dega, excla);
  k_gemm1<<<(NTILES + 3) / 4, 256, 0, stream>>>(x, bfragG, dega, h1p);
  k_agg1 <<<NB, 512, 0, stream>>>(pairs, gcur, dega, excla, h1p, b1, W2, gfp);
  k_agg2 <<<NB, 512, 0, stream>>>(pairs, gcur, dega, excla, gfp, b2, out);
}